// Round 1
// baseline (2891.691 us; speedup 1.0000x reference)
//
#include <hip/hip_runtime.h>

#define N_NODES 50000
#define N_EDGES 800000
#define IN_SIZE 128
#define HIDDEN 128
#define OUT_SIZE 64

// ---------------- degree counting ----------------
__global__ __launch_bounds__(256) void deg_kernel(const int* __restrict__ src,
                                                  const int* __restrict__ dst,
                                                  unsigned* __restrict__ deg_out,
                                                  unsigned* __restrict__ deg_in) {
    int e = blockIdx.x * 256 + threadIdx.x;
    if (e < N_EDGES) {
        atomicAdd(&deg_out[src[e]], 1u);
        atomicAdd(&deg_in[dst[e]], 1u);
    }
}

__global__ __launch_bounds__(256) void norm_kernel(const unsigned* __restrict__ deg_out,
                                                   const unsigned* __restrict__ deg_in,
                                                   float* __restrict__ norm_out,
                                                   float* __restrict__ norm_in) {
    int n = blockIdx.x * 256 + threadIdx.x;
    if (n < N_NODES) {
        unsigned dо = deg_out[n]; if (dо == 0u) dо = 1u;
        unsigned di = deg_in[n];  if (di == 0u) di = 1u;
        norm_out[n] = rsqrtf((float)dо);
        norm_in[n]  = rsqrtf((float)di);
    }
}

// ---------------- SpMM: agg[dst] += x[src] * (scale ? scale[src] : 1) ----------------
// 8 edges per 256-thread block; 32 lanes per edge, each lane handles 4 feats (float4).
__global__ __launch_bounds__(256) void spmm_kernel(const float* __restrict__ x,
                                                   const int* __restrict__ src,
                                                   const int* __restrict__ dst,
                                                   const float* __restrict__ scale,
                                                   float* __restrict__ agg) {
    const int t = threadIdx.x;
    const int e = blockIdx.x * 8 + (t >> 5);
    const int c = t & 31;
    if (e >= N_EDGES) return;
    const int s = src[e];
    const int d = dst[e];
    const float sc = scale ? scale[s] : 1.0f;
    float4 v = ((const float4*)(x + (size_t)s * 128))[c];
    float* o = agg + (size_t)d * 128 + c * 4;
    unsafeAtomicAdd(o + 0, v.x * sc);
    unsafeAtomicAdd(o + 1, v.y * sc);
    unsafeAtomicAdd(o + 2, v.z * sc);
    unsafeAtomicAdd(o + 3, v.w * sc);
}

// ---------------- GEMM1: h1p = relu(norm_in[n]*(agg @ W1) + b1) * norm_out[n] ----------------
// Tile: 32 nodes x 128 cols. 256 threads: tx in [0,32) -> 4 cols (float4), ty in [0,8) -> 4 nodes.
__global__ __launch_bounds__(256) void gemm1_kernel(const float* __restrict__ agg,
                                                    const float* __restrict__ W1,
                                                    const float* __restrict__ b1,
                                                    const float* __restrict__ norm_in,
                                                    const float* __restrict__ norm_out,
                                                    float* __restrict__ h1p) {
    __shared__ float sA[32][128];   // 16 KB
    __shared__ float sW[32][128];   // 16 KB (one K-chunk of W1)
    const int t  = threadIdx.x;
    const int tx = t & 31;
    const int ty = t >> 5;
    const int n0 = blockIdx.x * 32;

    // Load A tile (zeros past N)
    for (int i = t; i < 1024; i += 256) {       // 1024 float4 = 32 rows x 32 groups
        int n = i >> 5, c = i & 31;
        int gn = n0 + n;
        float4 v = make_float4(0.f, 0.f, 0.f, 0.f);
        if (gn < N_NODES) v = ((const float4*)(agg + (size_t)gn * 128))[c];
        ((float4*)sA[n])[c] = v;
    }

    float4 acc[4];
    #pragma unroll
    for (int i = 0; i < 4; ++i) acc[i] = make_float4(0.f, 0.f, 0.f, 0.f);

    for (int kc = 0; kc < 4; ++kc) {
        __syncthreads();
        for (int i = t; i < 1024; i += 256) {   // 32 k-rows x 32 groups
            int k = i >> 5, c = i & 31;
            ((float4*)sW[k])[c] = ((const float4*)(W1 + (size_t)(kc * 32 + k) * 128))[c];
        }
        __syncthreads();
        #pragma unroll 8
        for (int k = 0; k < 32; ++k) {
            float4 w = ((float4*)sW[k])[tx];
            #pragma unroll
            for (int ni = 0; ni < 4; ++ni) {
                float a = sA[ty * 4 + ni][kc * 32 + k];
                acc[ni].x = fmaf(a, w.x, acc[ni].x);
                acc[ni].y = fmaf(a, w.y, acc[ni].y);
                acc[ni].z = fmaf(a, w.z, acc[ni].z);
                acc[ni].w = fmaf(a, w.w, acc[ni].w);
            }
        }
    }

    float4 bb = ((const float4*)b1)[tx];
    #pragma unroll
    for (int ni = 0; ni < 4; ++ni) {
        int gn = n0 + ty * 4 + ni;
        if (gn < N_NODES) {
            float si = norm_in[gn];
            float so = norm_out[gn];
            float4 r;
            r.x = fmaxf(fmaf(acc[ni].x, si, bb.x), 0.f) * so;
            r.y = fmaxf(fmaf(acc[ni].y, si, bb.y), 0.f) * so;
            r.z = fmaxf(fmaf(acc[ni].z, si, bb.z), 0.f) * so;
            r.w = fmaxf(fmaf(acc[ni].w, si, bb.w), 0.f) * so;
            ((float4*)(h1p + (size_t)gn * 128))[tx] = r;
        }
    }
}

// ---------------- GEMM2: out = relu(norm_in[n]*(agg @ W2) + b2) ----------------
// Tile: 32 nodes x 64 cols. 256 threads: tx in [0,16) -> 4 cols, ty in [0,16) -> 2 nodes.
__global__ __launch_bounds__(256) void gemm2_kernel(const float* __restrict__ agg,
                                                    const float* __restrict__ W2,
                                                    const float* __restrict__ b2,
                                                    const float* __restrict__ norm_in,
                                                    float* __restrict__ out) {
    __shared__ float sA[32][128];   // 16 KB
    __shared__ float sW[128][64];   // 32 KB (full W2)
    const int t  = threadIdx.x;
    const int tx = t & 15;
    const int ty = t >> 4;
    const int n0 = blockIdx.x * 32;

    for (int i = t; i < 1024; i += 256) {
        int n = i >> 5, c = i & 31;
        int gn = n0 + n;
        float4 v = make_float4(0.f, 0.f, 0.f, 0.f);
        if (gn < N_NODES) v = ((const float4*)(agg + (size_t)gn * 128))[c];
        ((float4*)sA[n])[c] = v;
    }
    for (int i = t; i < 2048; i += 256) {       // 128 rows x 16 groups
        int k = i >> 4, c = i & 15;
        ((float4*)sW[k])[c] = ((const float4*)(W2 + (size_t)k * 64))[c];
    }
    __syncthreads();

    float4 a0 = make_float4(0.f, 0.f, 0.f, 0.f);
    float4 a1 = make_float4(0.f, 0.f, 0.f, 0.f);
    #pragma unroll 8
    for (int k = 0; k < 128; ++k) {
        float4 w = ((float4*)sW[k])[tx];
        float x0 = sA[ty * 2 + 0][k];
        float x1 = sA[ty * 2 + 1][k];
        a0.x = fmaf(x0, w.x, a0.x); a0.y = fmaf(x0, w.y, a0.y);
        a0.z = fmaf(x0, w.z, a0.z); a0.w = fmaf(x0, w.w, a0.w);
        a1.x = fmaf(x1, w.x, a1.x); a1.y = fmaf(x1, w.y, a1.y);
        a1.z = fmaf(x1, w.z, a1.z); a1.w = fmaf(x1, w.w, a1.w);
    }

    float4 bb = ((const float4*)b2)[tx];
    #pragma unroll
    for (int ni = 0; ni < 2; ++ni) {
        int gn = n0 + ty * 2 + ni;
        if (gn < N_NODES) {
            float si = norm_in[gn];
            float4 a = ni ? a1 : a0;
            float4 r;
            r.x = fmaxf(fmaf(a.x, si, bb.x), 0.f);
            r.y = fmaxf(fmaf(a.y, si, bb.y), 0.f);
            r.z = fmaxf(fmaf(a.z, si, bb.z), 0.f);
            r.w = fmaxf(fmaf(a.w, si, bb.w), 0.f);
            ((float4*)(out + (size_t)gn * 64))[tx] = r;
        }
    }
}

extern "C" void kernel_launch(void* const* d_in, const int* in_sizes, int n_in,
                              void* d_out, int out_size, void* d_ws, size_t ws_size,
                              hipStream_t stream) {
    const float* h  = (const float*)d_in[0];
    const float* W1 = (const float*)d_in[1];
    const float* b1 = (const float*)d_in[2];
    const float* W2 = (const float*)d_in[3];
    const float* b2 = (const float*)d_in[4];
    const int* src  = (const int*)d_in[5];
    const int* dst  = (const int*)d_in[6];
    float* out = (float*)d_out;

    char* ws = (char*)d_ws;
    size_t off = 0;
    auto alloc = [&](size_t bytes) {
        void* p = ws + off;
        off = (off + bytes + 255) & ~(size_t)255;
        return p;
    };
    unsigned* deg_out = (unsigned*)alloc(N_NODES * sizeof(unsigned));
    unsigned* deg_in  = (unsigned*)alloc(N_NODES * sizeof(unsigned));
    float* norm_out   = (float*)alloc(N_NODES * sizeof(float));
    float* norm_in    = (float*)alloc(N_NODES * sizeof(float));
    float* agg        = (float*)alloc((size_t)N_NODES * 128 * sizeof(float));
    float* h1p        = (float*)alloc((size_t)N_NODES * 128 * sizeof(float));

    // degrees + norms
    hipMemsetAsync(deg_out, 0, N_NODES * sizeof(unsigned), stream);
    hipMemsetAsync(deg_in,  0, N_NODES * sizeof(unsigned), stream);
    deg_kernel<<<(N_EDGES + 255) / 256, 256, 0, stream>>>(src, dst, deg_out, deg_in);
    norm_kernel<<<(N_NODES + 255) / 256, 256, 0, stream>>>(deg_out, deg_in, norm_out, norm_in);

    // layer 1
    hipMemsetAsync(agg, 0, (size_t)N_NODES * 128 * sizeof(float), stream);
    spmm_kernel<<<N_EDGES / 8, 256, 0, stream>>>(h, src, dst, norm_out, agg);
    gemm1_kernel<<<(N_NODES + 31) / 32, 256, 0, stream>>>(agg, W1, b1, norm_in, norm_out, h1p);

    // layer 2 (norm_out already folded into h1p)
    hipMemsetAsync(agg, 0, (size_t)N_NODES * 128 * sizeof(float), stream);
    spmm_kernel<<<N_EDGES / 8, 256, 0, stream>>>(h1p, src, dst, nullptr, agg);
    gemm2_kernel<<<(N_NODES + 31) / 32, 256, 0, stream>>>(agg, W2, b2, norm_in, out);
}

// Round 2
// 403.959 us; speedup vs baseline: 7.1584x; 7.1584x over previous
//
#include <hip/hip_runtime.h>

#define N_NODES 50000
#define N_EDGES 800000
#define IN_SIZE 128
#define HIDDEN 128
#define OUT_SIZE 64

// ---------------- degree counting ----------------
__global__ __launch_bounds__(256) void deg_kernel(const int* __restrict__ src,
                                                  const int* __restrict__ dst,
                                                  unsigned* __restrict__ deg_out,
                                                  unsigned* __restrict__ deg_in) {
    int e = blockIdx.x * 256 + threadIdx.x;
    if (e < N_EDGES) {
        atomicAdd(&deg_out[src[e]], 1u);
        atomicAdd(&deg_in[dst[e]], 1u);
    }
}

__global__ __launch_bounds__(256) void norm_kernel(const unsigned* __restrict__ deg_out,
                                                   const unsigned* __restrict__ deg_in,
                                                   float* __restrict__ norm_out,
                                                   float* __restrict__ norm_in) {
    int n = blockIdx.x * 256 + threadIdx.x;
    if (n < N_NODES) {
        unsigned a = deg_out[n]; if (a == 0u) a = 1u;
        unsigned b = deg_in[n];  if (b == 0u) b = 1u;
        norm_out[n] = rsqrtf((float)a);
        norm_in[n]  = rsqrtf((float)b);
    }
}

// ---------------- exclusive scan of deg_in -> row_ptr, cursor ----------------
// Single block, 1024 threads = 16 waves; wave-shuffle scan + cross-wave LDS.
__global__ __launch_bounds__(1024) void scan_kernel(const unsigned* __restrict__ deg,
                                                    int* __restrict__ row_ptr,
                                                    int* __restrict__ cursor) {
    __shared__ int wsum[16];
    __shared__ int carry;
    const int t = threadIdx.x;
    const int lane = t & 63, w = t >> 6;
    if (t == 0) carry = 0;
    __syncthreads();
    for (int base = 0; base < N_NODES; base += 1024) {
        int i = base + t;
        int v = (i < N_NODES) ? (int)deg[i] : 0;
        int incl = v;
        #pragma unroll
        for (int d = 1; d < 64; d <<= 1) {
            int u = __shfl_up(incl, d, 64);
            if (lane >= d) incl += u;
        }
        if (lane == 63) wsum[w] = incl;
        __syncthreads();
        int woff = 0, total = 0;
        #pragma unroll
        for (int j = 0; j < 16; ++j) {
            int s = wsum[j];
            if (j < w) woff += s;
            total += s;
        }
        int excl = carry + woff + incl - v;
        if (i < N_NODES) { row_ptr[i] = excl; cursor[i] = excl; }
        __syncthreads();
        if (t == 0) carry += total;
        __syncthreads();
    }
    if (t == 0) row_ptr[N_NODES] = N_EDGES;
}

// ---------------- scatter edges into CSR slots (grouped by dst) ----------------
__global__ __launch_bounds__(256) void scatter_kernel(const int* __restrict__ src,
                                                      const int* __restrict__ dst,
                                                      int* __restrict__ cursor,
                                                      int* __restrict__ eidx) {
    int e = blockIdx.x * 256 + threadIdx.x;
    if (e < N_EDGES) {
        int pos = atomicAdd(&cursor[dst[e]], 1);
        eidx[pos] = src[e];
    }
}

// ---------------- GEMM-A: t1 = (h * norm_out[row]) @ W1  (N x 128 @ 128 x 128) ----------------
__global__ __launch_bounds__(256) void gemmA_kernel(const float* __restrict__ h,
                                                    const float* __restrict__ W1,
                                                    const float* __restrict__ norm_out,
                                                    float* __restrict__ t1) {
    __shared__ float sA[32][128];
    __shared__ float sW[32][128];
    const int t  = threadIdx.x;
    const int tx = t & 31;
    const int ty = t >> 5;
    const int n0 = blockIdx.x * 32;

    for (int i = t; i < 1024; i += 256) {
        int n = i >> 5, c = i & 31;
        int gn = n0 + n;
        float4 v = make_float4(0.f, 0.f, 0.f, 0.f);
        if (gn < N_NODES) {
            v = ((const float4*)(h + (size_t)gn * 128))[c];
            float no = norm_out[gn];
            v.x *= no; v.y *= no; v.z *= no; v.w *= no;
        }
        ((float4*)sA[n])[c] = v;
    }

    float4 acc[4];
    #pragma unroll
    for (int i = 0; i < 4; ++i) acc[i] = make_float4(0.f, 0.f, 0.f, 0.f);

    for (int kc = 0; kc < 4; ++kc) {
        __syncthreads();
        for (int i = t; i < 1024; i += 256) {
            int k = i >> 5, c = i & 31;
            ((float4*)sW[k])[c] = ((const float4*)(W1 + (size_t)(kc * 32 + k) * 128))[c];
        }
        __syncthreads();
        #pragma unroll 8
        for (int k = 0; k < 32; ++k) {
            float4 w = ((float4*)sW[k])[tx];
            #pragma unroll
            for (int ni = 0; ni < 4; ++ni) {
                float a = sA[ty * 4 + ni][kc * 32 + k];
                acc[ni].x = fmaf(a, w.x, acc[ni].x);
                acc[ni].y = fmaf(a, w.y, acc[ni].y);
                acc[ni].z = fmaf(a, w.z, acc[ni].z);
                acc[ni].w = fmaf(a, w.w, acc[ni].w);
            }
        }
    }

    #pragma unroll
    for (int ni = 0; ni < 4; ++ni) {
        int gn = n0 + ty * 4 + ni;
        if (gn < N_NODES) ((float4*)(t1 + (size_t)gn * 128))[tx] = acc[ni];
    }
}

// ---------------- GEMM-B: t2 = h1p @ W2  (N x 128 @ 128 x 64) ----------------
__global__ __launch_bounds__(256) void gemmB_kernel(const float* __restrict__ h1p,
                                                    const float* __restrict__ W2,
                                                    float* __restrict__ t2) {
    __shared__ float sA[32][128];
    __shared__ float sW[128][64];
    const int t  = threadIdx.x;
    const int tx = t & 15;
    const int ty = t >> 4;
    const int n0 = blockIdx.x * 32;

    for (int i = t; i < 1024; i += 256) {
        int n = i >> 5, c = i & 31;
        int gn = n0 + n;
        float4 v = make_float4(0.f, 0.f, 0.f, 0.f);
        if (gn < N_NODES) v = ((const float4*)(h1p + (size_t)gn * 128))[c];
        ((float4*)sA[n])[c] = v;
    }
    for (int i = t; i < 2048; i += 256) {
        int k = i >> 4, c = i & 15;
        ((float4*)sW[k])[c] = ((const float4*)(W2 + (size_t)k * 64))[c];
    }
    __syncthreads();

    float4 a0 = make_float4(0.f, 0.f, 0.f, 0.f);
    float4 a1 = make_float4(0.f, 0.f, 0.f, 0.f);
    #pragma unroll 8
    for (int k = 0; k < 128; ++k) {
        float4 w = ((float4*)sW[k])[tx];
        float x0 = sA[ty * 2 + 0][k];
        float x1 = sA[ty * 2 + 1][k];
        a0.x = fmaf(x0, w.x, a0.x); a0.y = fmaf(x0, w.y, a0.y);
        a0.z = fmaf(x0, w.z, a0.z); a0.w = fmaf(x0, w.w, a0.w);
        a1.x = fmaf(x1, w.x, a1.x); a1.y = fmaf(x1, w.y, a1.y);
        a1.z = fmaf(x1, w.z, a1.z); a1.w = fmaf(x1, w.w, a1.w);
    }

    #pragma unroll
    for (int ni = 0; ni < 2; ++ni) {
        int gn = n0 + ty * 2 + ni;
        if (gn < N_NODES) ((float4*)(t2 + (size_t)gn * 64))[tx] = ni ? a1 : a0;
    }
}

// ---------------- pull aggregation, 128 feats: one wave per node ----------------
// h1p[n] = relu(norm_in[n] * sum_{s->n} t1[s] + b1) * norm_out[n]
__global__ __launch_bounds__(256) void pull128_kernel(const float* __restrict__ x,
                                                      const int* __restrict__ row_ptr,
                                                      const int* __restrict__ eidx,
                                                      const float* __restrict__ b1,
                                                      const float* __restrict__ norm_in,
                                                      const float* __restrict__ norm_out,
                                                      float* __restrict__ out) {
    int node = blockIdx.x * 4 + (threadIdx.x >> 6);
    node = __builtin_amdgcn_readfirstlane(node);
    const int lane = threadIdx.x & 63;
    const int beg = row_ptr[node];
    const int end = row_ptr[node + 1];

    float2 acc0 = make_float2(0.f, 0.f);
    float2 acc1 = make_float2(0.f, 0.f);
    int j = beg;
    for (; j + 1 < end; j += 2) {
        int s0 = eidx[j];
        int s1 = eidx[j + 1];
        float2 v0 = ((const float2*)(x + (size_t)s0 * 128))[lane];
        float2 v1 = ((const float2*)(x + (size_t)s1 * 128))[lane];
        acc0.x += v0.x; acc0.y += v0.y;
        acc1.x += v1.x; acc1.y += v1.y;
    }
    if (j < end) {
        int s0 = eidx[j];
        float2 v0 = ((const float2*)(x + (size_t)s0 * 128))[lane];
        acc0.x += v0.x; acc0.y += v0.y;
    }
    float ni = norm_in[node];
    float no = norm_out[node];
    float2 bb = ((const float2*)b1)[lane];
    float2 r;
    r.x = fmaxf(fmaf(acc0.x + acc1.x, ni, bb.x), 0.f) * no;
    r.y = fmaxf(fmaf(acc0.y + acc1.y, ni, bb.y), 0.f) * no;
    ((float2*)(out + (size_t)node * 128))[lane] = r;
}

// ---------------- pull aggregation, 64 feats: one wave per node, half-wave per edge ----------------
// out[n] = relu(norm_in[n] * sum_{s->n} t2[s] + b2)
__global__ __launch_bounds__(256) void pull64_kernel(const float* __restrict__ x,
                                                     const int* __restrict__ row_ptr,
                                                     const int* __restrict__ eidx,
                                                     const float* __restrict__ b2,
                                                     const float* __restrict__ norm_in,
                                                     float* __restrict__ out) {
    int node = blockIdx.x * 4 + (threadIdx.x >> 6);
    node = __builtin_amdgcn_readfirstlane(node);
    const int lane = threadIdx.x & 63;
    const int half = lane >> 5;     // 0: even edges, 1: odd edges
    const int fl = lane & 31;       // feature group (float2)
    const int beg = row_ptr[node];
    const int end = row_ptr[node + 1];

    float2 acc = make_float2(0.f, 0.f);
    for (int j = beg + half; j < end; j += 2) {
        int s = eidx[j];
        float2 v = ((const float2*)(x + (size_t)s * 64))[fl];
        acc.x += v.x; acc.y += v.y;
    }
    acc.x += __shfl_xor(acc.x, 32, 64);
    acc.y += __shfl_xor(acc.y, 32, 64);
    if (half == 0) {
        float ni = norm_in[node];
        float2 bb = ((const float2*)b2)[fl];
        float2 r;
        r.x = fmaxf(fmaf(acc.x, ni, bb.x), 0.f);
        r.y = fmaxf(fmaf(acc.y, ni, bb.y), 0.f);
        ((float2*)(out + (size_t)node * 64))[fl] = r;
    }
}

extern "C" void kernel_launch(void* const* d_in, const int* in_sizes, int n_in,
                              void* d_out, int out_size, void* d_ws, size_t ws_size,
                              hipStream_t stream) {
    const float* h  = (const float*)d_in[0];
    const float* W1 = (const float*)d_in[1];
    const float* b1 = (const float*)d_in[2];
    const float* W2 = (const float*)d_in[3];
    const float* b2 = (const float*)d_in[4];
    const int* src  = (const int*)d_in[5];
    const int* dst  = (const int*)d_in[6];
    float* out = (float*)d_out;

    char* ws = (char*)d_ws;
    size_t off = 0;
    auto alloc = [&](size_t bytes) {
        void* p = ws + off;
        off = (off + bytes + 255) & ~(size_t)255;
        return p;
    };
    unsigned* deg_out = (unsigned*)alloc(N_NODES * sizeof(unsigned));
    unsigned* deg_in  = (unsigned*)alloc(N_NODES * sizeof(unsigned));
    float* norm_out   = (float*)alloc(N_NODES * sizeof(float));
    float* norm_in    = (float*)alloc(N_NODES * sizeof(float));
    int* row_ptr      = (int*)alloc((N_NODES + 1) * sizeof(int));
    int* cursor       = (int*)alloc(N_NODES * sizeof(int));
    int* eidx         = (int*)alloc((size_t)N_EDGES * sizeof(int));
    float* t1         = (float*)alloc((size_t)N_NODES * 128 * sizeof(float)); // reused as t2
    float* h1p        = (float*)alloc((size_t)N_NODES * 128 * sizeof(float));
    float* t2         = t1;  // t1 dead after pull128

    // degrees + norms
    hipMemsetAsync(deg_out, 0, N_NODES * sizeof(unsigned), stream);
    hipMemsetAsync(deg_in,  0, N_NODES * sizeof(unsigned), stream);
    deg_kernel<<<(N_EDGES + 255) / 256, 256, 0, stream>>>(src, dst, deg_out, deg_in);
    norm_kernel<<<(N_NODES + 255) / 256, 256, 0, stream>>>(deg_out, deg_in, norm_out, norm_in);

    // CSR build (reused by both layers)
    scan_kernel<<<1, 1024, 0, stream>>>(deg_in, row_ptr, cursor);
    scatter_kernel<<<(N_EDGES + 255) / 256, 256, 0, stream>>>(src, dst, cursor, eidx);

    // layer 1: transform-first, then pull
    gemmA_kernel<<<(N_NODES + 31) / 32, 256, 0, stream>>>(h, W1, norm_out, t1);
    pull128_kernel<<<N_NODES / 4, 256, 0, stream>>>(t1, row_ptr, eidx, b1, norm_in, norm_out, h1p);

    // layer 2
    gemmB_kernel<<<(N_NODES + 31) / 32, 256, 0, stream>>>(h1p, W2, t2);
    pull64_kernel<<<N_NODES / 4, 256, 0, stream>>>(t2, row_ptr, eidx, b2, norm_in, out);
}

// Round 3
// 313.444 us; speedup vs baseline: 9.2255x; 1.2888x over previous
//
#include <hip/hip_runtime.h>

#define N_NODES 50000
#define N_EDGES 800000
#define IN_SIZE 128
#define HIDDEN 128
#define OUT_SIZE 64

#define DEG_PAD 16          // one deg_in counter per 64B cacheline
#define NREP 8              // deg_out replicas
#define REP_STRIDE 50176    // per-replica stride (ints)
#define SCAN_BLK 1024
#define SCAN_GRID 49        // 49*1024 = 50176 >= 50000

// ---- pass 1: deg_in (padded, with-return -> rank) + deg_out (replicated, fire-and-forget) ----
__global__ __launch_bounds__(256) void deg_rank_kernel(const int* __restrict__ src,
                                                       const int* __restrict__ dst,
                                                       int* __restrict__ deg_in_pad,
                                                       unsigned* __restrict__ deg_out_rep,
                                                       int* __restrict__ rank) {
    int e = blockIdx.x * 256 + threadIdx.x;
    if (e < N_EDGES) {
        int s = src[e];
        int d = dst[e];
        rank[e] = atomicAdd(&deg_in_pad[(size_t)d * DEG_PAD], 1);
        atomicAdd(&deg_out_rep[(size_t)(blockIdx.x & (NREP - 1)) * REP_STRIDE + s], 1u);
    }
}

// ---- scan phase 1: per-block exclusive scan of padded deg_in, emit block sums ----
__global__ __launch_bounds__(SCAN_BLK) void scan1_kernel(const int* __restrict__ deg_in_pad,
                                                         int* __restrict__ row_ptr,
                                                         int* __restrict__ bsum) {
    __shared__ int wsum[16];
    const int t = threadIdx.x, lane = t & 63, w = t >> 6;
    const int i = blockIdx.x * SCAN_BLK + t;
    int v = (i < N_NODES) ? deg_in_pad[(size_t)i * DEG_PAD] : 0;
    int incl = v;
    #pragma unroll
    for (int d = 1; d < 64; d <<= 1) {
        int u = __shfl_up(incl, d, 64);
        if (lane >= d) incl += u;
    }
    if (lane == 63) wsum[w] = incl;
    __syncthreads();
    int woff = 0, total = 0;
    #pragma unroll
    for (int j = 0; j < 16; ++j) {
        int s = wsum[j];
        if (j < w) woff += s;
        total += s;
    }
    if (i < N_NODES) row_ptr[i] = woff + incl - v;
    if (t == 0) bsum[blockIdx.x] = total;
}

// ---- scan phase 2: exclusive scan of 49 block sums (single wave) ----
__global__ __launch_bounds__(64) void scan2_kernel(int* __restrict__ bsum) {
    const int t = threadIdx.x;
    int v = (t < SCAN_GRID) ? bsum[t] : 0;
    int incl = v;
    #pragma unroll
    for (int d = 1; d < 64; d <<= 1) {
        int u = __shfl_up(incl, d, 64);
        if (t >= d) incl += u;
    }
    if (t < SCAN_GRID) bsum[t] = incl - v;
}

// ---- scan phase 3: add block offsets ----
__global__ __launch_bounds__(SCAN_BLK) void scan3_kernel(int* __restrict__ row_ptr,
                                                         const int* __restrict__ bsum) {
    const int i = blockIdx.x * SCAN_BLK + threadIdx.x;
    if (i < N_NODES) row_ptr[i] += bsum[blockIdx.x];
    if (i == 0) row_ptr[N_NODES] = N_EDGES;
}

// ---- pass 2: atomic-free CSR placement ----
__global__ __launch_bounds__(256) void place_kernel(const int* __restrict__ src,
                                                    const int* __restrict__ dst,
                                                    const int* __restrict__ row_ptr,
                                                    const int* __restrict__ rank,
                                                    int* __restrict__ eidx) {
    int e = blockIdx.x * 256 + threadIdx.x;
    if (e < N_EDGES) eidx[row_ptr[dst[e]] + rank[e]] = src[e];
}

// ---- norms: sum replicas, clamp, rsqrt ----
__global__ __launch_bounds__(256) void norm_kernel(const int* __restrict__ deg_in_pad,
                                                   const unsigned* __restrict__ deg_out_rep,
                                                   float* __restrict__ norm_out,
                                                   float* __restrict__ norm_in) {
    int n = blockIdx.x * 256 + threadIdx.x;
    if (n < N_NODES) {
        unsigned a = 0;
        #pragma unroll
        for (int r = 0; r < NREP; ++r) a += deg_out_rep[(size_t)r * REP_STRIDE + n];
        int b = deg_in_pad[(size_t)n * DEG_PAD];
        if (a == 0u) a = 1u;
        if (b == 0) b = 1;
        norm_out[n] = rsqrtf((float)a);
        norm_in[n]  = rsqrtf((float)b);
    }
}

// ---------------- GEMM-A: t1 = (h * norm_out[row]) @ W1  (N x 128 @ 128 x 128) ----------------
__global__ __launch_bounds__(256) void gemmA_kernel(const float* __restrict__ h,
                                                    const float* __restrict__ W1,
                                                    const float* __restrict__ norm_out,
                                                    float* __restrict__ t1) {
    __shared__ float sA[32][128];
    __shared__ float sW[32][128];
    const int t  = threadIdx.x;
    const int tx = t & 31;
    const int ty = t >> 5;
    const int n0 = blockIdx.x * 32;

    for (int i = t; i < 1024; i += 256) {
        int n = i >> 5, c = i & 31;
        int gn = n0 + n;
        float4 v = make_float4(0.f, 0.f, 0.f, 0.f);
        if (gn < N_NODES) {
            v = ((const float4*)(h + (size_t)gn * 128))[c];
            float no = norm_out[gn];
            v.x *= no; v.y *= no; v.z *= no; v.w *= no;
        }
        ((float4*)sA[n])[c] = v;
    }

    float4 acc[4];
    #pragma unroll
    for (int i = 0; i < 4; ++i) acc[i] = make_float4(0.f, 0.f, 0.f, 0.f);

    for (int kc = 0; kc < 4; ++kc) {
        __syncthreads();
        for (int i = t; i < 1024; i += 256) {
            int k = i >> 5, c = i & 31;
            ((float4*)sW[k])[c] = ((const float4*)(W1 + (size_t)(kc * 32 + k) * 128))[c];
        }
        __syncthreads();
        #pragma unroll 8
        for (int k = 0; k < 32; ++k) {
            float4 w = ((float4*)sW[k])[tx];
            #pragma unroll
            for (int ni = 0; ni < 4; ++ni) {
                float a = sA[ty * 4 + ni][kc * 32 + k];
                acc[ni].x = fmaf(a, w.x, acc[ni].x);
                acc[ni].y = fmaf(a, w.y, acc[ni].y);
                acc[ni].z = fmaf(a, w.z, acc[ni].z);
                acc[ni].w = fmaf(a, w.w, acc[ni].w);
            }
        }
    }

    #pragma unroll
    for (int ni = 0; ni < 4; ++ni) {
        int gn = n0 + ty * 4 + ni;
        if (gn < N_NODES) ((float4*)(t1 + (size_t)gn * 128))[tx] = acc[ni];
    }
}

// ---------------- GEMM-B: t2 = h1p @ W2  (N x 128 @ 128 x 64) ----------------
__global__ __launch_bounds__(256) void gemmB_kernel(const float* __restrict__ h1p,
                                                    const float* __restrict__ W2,
                                                    float* __restrict__ t2) {
    __shared__ float sA[32][128];
    __shared__ float sW[128][64];
    const int t  = threadIdx.x;
    const int tx = t & 15;
    const int ty = t >> 4;
    const int n0 = blockIdx.x * 32;

    for (int i = t; i < 1024; i += 256) {
        int n = i >> 5, c = i & 31;
        int gn = n0 + n;
        float4 v = make_float4(0.f, 0.f, 0.f, 0.f);
        if (gn < N_NODES) v = ((const float4*)(h1p + (size_t)gn * 128))[c];
        ((float4*)sA[n])[c] = v;
    }
    for (int i = t; i < 2048; i += 256) {
        int k = i >> 4, c = i & 15;
        ((float4*)sW[k])[c] = ((const float4*)(W2 + (size_t)k * 64))[c];
    }
    __syncthreads();

    float4 a0 = make_float4(0.f, 0.f, 0.f, 0.f);
    float4 a1 = make_float4(0.f, 0.f, 0.f, 0.f);
    #pragma unroll 8
    for (int k = 0; k < 128; ++k) {
        float4 w = ((float4*)sW[k])[tx];
        float x0 = sA[ty * 2 + 0][k];
        float x1 = sA[ty * 2 + 1][k];
        a0.x = fmaf(x0, w.x, a0.x); a0.y = fmaf(x0, w.y, a0.y);
        a0.z = fmaf(x0, w.z, a0.z); a0.w = fmaf(x0, w.w, a0.w);
        a1.x = fmaf(x1, w.x, a1.x); a1.y = fmaf(x1, w.y, a1.y);
        a1.z = fmaf(x1, w.z, a1.z); a1.w = fmaf(x1, w.w, a1.w);
    }

    #pragma unroll
    for (int ni = 0; ni < 2; ++ni) {
        int gn = n0 + ty * 2 + ni;
        if (gn < N_NODES) ((float4*)(t2 + (size_t)gn * 64))[tx] = ni ? a1 : a0;
    }
}

// ---------------- pull aggregation, 128 feats: one wave per node ----------------
// h1p[n] = relu(norm_in[n] * sum_{s->n} t1[s] + b1) * norm_out[n]
__global__ __launch_bounds__(256) void pull128_kernel(const float* __restrict__ x,
                                                      const int* __restrict__ row_ptr,
                                                      const int* __restrict__ eidx,
                                                      const float* __restrict__ b1,
                                                      const float* __restrict__ norm_in,
                                                      const float* __restrict__ norm_out,
                                                      float* __restrict__ out) {
    int node = blockIdx.x * 4 + (threadIdx.x >> 6);
    node = __builtin_amdgcn_readfirstlane(node);
    const int lane = threadIdx.x & 63;
    const int beg = row_ptr[node];
    const int end = row_ptr[node + 1];

    float2 acc0 = make_float2(0.f, 0.f);
    float2 acc1 = make_float2(0.f, 0.f);
    float2 acc2 = make_float2(0.f, 0.f);
    float2 acc3 = make_float2(0.f, 0.f);
    int j = beg;
    for (; j + 3 < end; j += 4) {
        int s0 = eidx[j], s1 = eidx[j + 1], s2 = eidx[j + 2], s3 = eidx[j + 3];
        float2 v0 = ((const float2*)(x + (size_t)s0 * 128))[lane];
        float2 v1 = ((const float2*)(x + (size_t)s1 * 128))[lane];
        float2 v2 = ((const float2*)(x + (size_t)s2 * 128))[lane];
        float2 v3 = ((const float2*)(x + (size_t)s3 * 128))[lane];
        acc0.x += v0.x; acc0.y += v0.y;
        acc1.x += v1.x; acc1.y += v1.y;
        acc2.x += v2.x; acc2.y += v2.y;
        acc3.x += v3.x; acc3.y += v3.y;
    }
    for (; j < end; ++j) {
        int s0 = eidx[j];
        float2 v0 = ((const float2*)(x + (size_t)s0 * 128))[lane];
        acc0.x += v0.x; acc0.y += v0.y;
    }
    float ni = norm_in[node];
    float no = norm_out[node];
    float2 bb = ((const float2*)b1)[lane];
    float sx = (acc0.x + acc1.x) + (acc2.x + acc3.x);
    float sy = (acc0.y + acc1.y) + (acc2.y + acc3.y);
    float2 r;
    r.x = fmaxf(fmaf(sx, ni, bb.x), 0.f) * no;
    r.y = fmaxf(fmaf(sy, ni, bb.y), 0.f) * no;
    ((float2*)(out + (size_t)node * 128))[lane] = r;
}

// ---------------- pull aggregation, 64 feats: one wave per node, half-wave per edge ----------------
// out[n] = relu(norm_in[n] * sum_{s->n} t2[s] + b2)
__global__ __launch_bounds__(256) void pull64_kernel(const float* __restrict__ x,
                                                     const int* __restrict__ row_ptr,
                                                     const int* __restrict__ eidx,
                                                     const float* __restrict__ b2,
                                                     const float* __restrict__ norm_in,
                                                     float* __restrict__ out) {
    int node = blockIdx.x * 4 + (threadIdx.x >> 6);
    node = __builtin_amdgcn_readfirstlane(node);
    const int lane = threadIdx.x & 63;
    const int half = lane >> 5;     // 0: even edges, 1: odd edges
    const int fl = lane & 31;       // feature group (float2)
    const int beg = row_ptr[node];
    const int end = row_ptr[node + 1];

    float2 acc0 = make_float2(0.f, 0.f);
    float2 acc1 = make_float2(0.f, 0.f);
    int j = beg + half;
    for (; j + 2 < end; j += 4) {
        int s0 = eidx[j], s1 = eidx[j + 2];
        float2 v0 = ((const float2*)(x + (size_t)s0 * 64))[fl];
        float2 v1 = ((const float2*)(x + (size_t)s1 * 64))[fl];
        acc0.x += v0.x; acc0.y += v0.y;
        acc1.x += v1.x; acc1.y += v1.y;
    }
    if (j < end) {
        int s0 = eidx[j];
        float2 v0 = ((const float2*)(x + (size_t)s0 * 64))[fl];
        acc0.x += v0.x; acc0.y += v0.y;
    }
    float ax = acc0.x + acc1.x, ay = acc0.y + acc1.y;
    ax += __shfl_xor(ax, 32, 64);
    ay += __shfl_xor(ay, 32, 64);
    if (half == 0) {
        float ni = norm_in[node];
        float2 bb = ((const float2*)b2)[fl];
        float2 r;
        r.x = fmaxf(fmaf(ax, ni, bb.x), 0.f);
        r.y = fmaxf(fmaf(ay, ni, bb.y), 0.f);
        ((float2*)(out + (size_t)node * 64))[fl] = r;
    }
}

extern "C" void kernel_launch(void* const* d_in, const int* in_sizes, int n_in,
                              void* d_out, int out_size, void* d_ws, size_t ws_size,
                              hipStream_t stream) {
    const float* h  = (const float*)d_in[0];
    const float* W1 = (const float*)d_in[1];
    const float* b1 = (const float*)d_in[2];
    const float* W2 = (const float*)d_in[3];
    const float* b2 = (const float*)d_in[4];
    const int* src  = (const int*)d_in[5];
    const int* dst  = (const int*)d_in[6];
    float* out = (float*)d_out;

    char* ws = (char*)d_ws;
    size_t off = 0;
    auto alloc = [&](size_t bytes) {
        void* p = ws + off;
        off = (off + bytes + 255) & ~(size_t)255;
        return p;
    };
    int* deg_in_pad   = (int*)alloc((size_t)N_NODES * DEG_PAD * sizeof(int));      // 3.2 MB
    unsigned* deg_rep = (unsigned*)alloc((size_t)NREP * REP_STRIDE * sizeof(int)); // 1.6 MB
    float* norm_out   = (float*)alloc(N_NODES * sizeof(float));
    float* norm_in    = (float*)alloc(N_NODES * sizeof(float));
    int* row_ptr      = (int*)alloc((N_NODES + 1) * sizeof(int));
    int* bsum         = (int*)alloc(SCAN_GRID * sizeof(int));
    int* eidx         = (int*)alloc((size_t)N_EDGES * sizeof(int));                // 3.2 MB
    float* t1         = (float*)alloc((size_t)N_NODES * 128 * sizeof(float));      // 25.6 MB (reused as t2)
    float* h1p        = (float*)alloc((size_t)N_NODES * 128 * sizeof(float));      // 25.6 MB
    int* rank         = (int*)h1p;   // rank dead before pull128 writes h1p
    float* t2         = t1;          // t1 dead after pull128

    // pass 1: degrees (+rank capture)
    hipMemsetAsync(deg_in_pad, 0, (size_t)N_NODES * DEG_PAD * sizeof(int), stream);
    hipMemsetAsync(deg_rep, 0, (size_t)NREP * REP_STRIDE * sizeof(int), stream);
    deg_rank_kernel<<<(N_EDGES + 255) / 256, 256, 0, stream>>>(src, dst, deg_in_pad, deg_rep, rank);

    // parallel scan -> row_ptr
    scan1_kernel<<<SCAN_GRID, SCAN_BLK, 0, stream>>>(deg_in_pad, row_ptr, bsum);
    scan2_kernel<<<1, 64, 0, stream>>>(bsum);
    scan3_kernel<<<SCAN_GRID, SCAN_BLK, 0, stream>>>(row_ptr, bsum);

    // pass 2: atomic-free placement
    place_kernel<<<(N_EDGES + 255) / 256, 256, 0, stream>>>(src, dst, row_ptr, rank, eidx);

    // norms
    norm_kernel<<<(N_NODES + 255) / 256, 256, 0, stream>>>(deg_in_pad, deg_rep, norm_out, norm_in);

    // layer 1: transform-first, then pull
    gemmA_kernel<<<(N_NODES + 31) / 32, 256, 0, stream>>>(h, W1, norm_out, t1);
    pull128_kernel<<<N_NODES / 4, 256, 0, stream>>>(t1, row_ptr, eidx, b1, norm_in, norm_out, h1p);

    // layer 2
    gemmB_kernel<<<(N_NODES + 31) / 32, 256, 0, stream>>>(h1p, W2, t2);
    pull64_kernel<<<N_NODES / 4, 256, 0, stream>>>(t2, row_ptr, eidx, b2, norm_in, out);
}

// Round 4
// 303.298 us; speedup vs baseline: 9.5342x; 1.0335x over previous
//
#include <hip/hip_runtime.h>

#define N_NODES 50000
#define N_EDGES 800000
#define IN_SIZE 128
#define HIDDEN 128
#define OUT_SIZE 64

#define DEG_BLOCKS 3125     // 3125*256 = 800000 edges exactly
#define GEMMA_BLOCKS 1563   // ceil(50000/32)
#define SCAN_BLK 1024
#define SCAN_GRID 49        // 49*1024 = 50176 >= 50000

// ---- fused launch 1: deg+rank blocks, then gemmA blocks (independent work) ----
// deg part:  rank[e] = deg_in[dst]++;  deg_out[src]++   (device atomics, GPU mostly idle)
// gemmA part: t1 = h @ W1 (no norm fold; norm_out applied per-edge in pull128)
__global__ __launch_bounds__(256) void fused1_kernel(const int* __restrict__ src,
                                                     const int* __restrict__ dst,
                                                     int* __restrict__ deg_in,
                                                     unsigned* __restrict__ deg_out,
                                                     int* __restrict__ rank,
                                                     const float* __restrict__ h,
                                                     const float* __restrict__ W1,
                                                     float* __restrict__ t1) {
    __shared__ float sA[32][128];
    __shared__ float sW[32][128];

    if (blockIdx.x < DEG_BLOCKS) {
        int e = blockIdx.x * 256 + threadIdx.x;   // always < N_EDGES
        int s = src[e];
        int d = dst[e];
        rank[e] = atomicAdd(&deg_in[d], 1);
        atomicAdd(&deg_out[s], 1u);
        return;
    }

    const int t  = threadIdx.x;
    const int tx = t & 31;
    const int ty = t >> 5;
    const int n0 = (blockIdx.x - DEG_BLOCKS) * 32;

    for (int i = t; i < 1024; i += 256) {
        int n = i >> 5, c = i & 31;
        int gn = n0 + n;
        float4 v = make_float4(0.f, 0.f, 0.f, 0.f);
        if (gn < N_NODES) v = ((const float4*)(h + (size_t)gn * 128))[c];
        ((float4*)sA[n])[c] = v;
    }

    float4 acc[4];
    #pragma unroll
    for (int i = 0; i < 4; ++i) acc[i] = make_float4(0.f, 0.f, 0.f, 0.f);

    for (int kc = 0; kc < 4; ++kc) {
        __syncthreads();
        for (int i = t; i < 1024; i += 256) {
            int k = i >> 5, c = i & 31;
            ((float4*)sW[k])[c] = ((const float4*)(W1 + (size_t)(kc * 32 + k) * 128))[c];
        }
        __syncthreads();
        #pragma unroll 8
        for (int k = 0; k < 32; ++k) {
            float4 w = ((float4*)sW[k])[tx];
            #pragma unroll
            for (int ni = 0; ni < 4; ++ni) {
                float a = sA[ty * 4 + ni][kc * 32 + k];
                acc[ni].x = fmaf(a, w.x, acc[ni].x);
                acc[ni].y = fmaf(a, w.y, acc[ni].y);
                acc[ni].z = fmaf(a, w.z, acc[ni].z);
                acc[ni].w = fmaf(a, w.w, acc[ni].w);
            }
        }
    }

    #pragma unroll
    for (int ni = 0; ni < 4; ++ni) {
        int gn = n0 + ty * 4 + ni;
        if (gn < N_NODES) ((float4*)(t1 + (size_t)gn * 128))[tx] = acc[ni];
    }
}

// ---- scan phase 1: per-block exclusive scan of deg_in, emit block sums ----
__global__ __launch_bounds__(SCAN_BLK) void scan1_kernel(const int* __restrict__ deg_in,
                                                         int* __restrict__ row_ptr,
                                                         int* __restrict__ bsum) {
    __shared__ int wsum[16];
    const int t = threadIdx.x, lane = t & 63, w = t >> 6;
    const int i = blockIdx.x * SCAN_BLK + t;
    int v = (i < N_NODES) ? deg_in[i] : 0;
    int incl = v;
    #pragma unroll
    for (int d = 1; d < 64; d <<= 1) {
        int u = __shfl_up(incl, d, 64);
        if (lane >= d) incl += u;
    }
    if (lane == 63) wsum[w] = incl;
    __syncthreads();
    int woff = 0, total = 0;
    #pragma unroll
    for (int j = 0; j < 16; ++j) {
        int s = wsum[j];
        if (j < w) woff += s;
        total += s;
    }
    if (i < N_NODES) row_ptr[i] = woff + incl - v;
    if (t == 0) bsum[blockIdx.x] = total;
}

// ---- scan phase 2: exclusive scan of 49 block sums (single wave) ----
__global__ __launch_bounds__(64) void scan2_kernel(int* __restrict__ bsum) {
    const int t = threadIdx.x;
    int v = (t < SCAN_GRID) ? bsum[t] : 0;
    int incl = v;
    #pragma unroll
    for (int d = 1; d < 64; d <<= 1) {
        int u = __shfl_up(incl, d, 64);
        if (t >= d) incl += u;
    }
    if (t < SCAN_GRID) bsum[t] = incl - v;
}

// ---- scan phase 3 + norms: add block offsets; compute rsqrt norms ----
__global__ __launch_bounds__(SCAN_BLK) void scan3_norm_kernel(int* __restrict__ row_ptr,
                                                              const int* __restrict__ bsum,
                                                              const int* __restrict__ deg_in,
                                                              const unsigned* __restrict__ deg_out,
                                                              float* __restrict__ norm_out,
                                                              float* __restrict__ norm_in) {
    const int i = blockIdx.x * SCAN_BLK + threadIdx.x;
    if (i < N_NODES) {
        row_ptr[i] += bsum[blockIdx.x];
        unsigned a = deg_out[i]; if (a == 0u) a = 1u;
        int b = deg_in[i];       if (b == 0)  b = 1;
        norm_out[i] = rsqrtf((float)a);
        norm_in[i]  = rsqrtf((float)b);
    }
    if (i == 0) row_ptr[N_NODES] = N_EDGES;
}

// ---- atomic-free CSR placement ----
__global__ __launch_bounds__(256) void place_kernel(const int* __restrict__ src,
                                                    const int* __restrict__ dst,
                                                    const int* __restrict__ row_ptr,
                                                    const int* __restrict__ rank,
                                                    int* __restrict__ eidx) {
    int e = blockIdx.x * 256 + threadIdx.x;
    if (e < N_EDGES) eidx[row_ptr[dst[e]] + rank[e]] = src[e];
}

// ---------------- GEMM-B: t2 = h1p @ W2  (N x 128 @ 128 x 64) ----------------
__global__ __launch_bounds__(256) void gemmB_kernel(const float* __restrict__ h1p,
                                                    const float* __restrict__ W2,
                                                    float* __restrict__ t2) {
    __shared__ float sA[32][128];
    __shared__ float sW[128][64];
    const int t  = threadIdx.x;
    const int tx = t & 15;
    const int ty = t >> 4;
    const int n0 = blockIdx.x * 32;

    for (int i = t; i < 1024; i += 256) {
        int n = i >> 5, c = i & 31;
        int gn = n0 + n;
        float4 v = make_float4(0.f, 0.f, 0.f, 0.f);
        if (gn < N_NODES) v = ((const float4*)(h1p + (size_t)gn * 128))[c];
        ((float4*)sA[n])[c] = v;
    }
    for (int i = t; i < 2048; i += 256) {
        int k = i >> 4, c = i & 15;
        ((float4*)sW[k])[c] = ((const float4*)(W2 + (size_t)k * 64))[c];
    }
    __syncthreads();

    float4 a0 = make_float4(0.f, 0.f, 0.f, 0.f);
    float4 a1 = make_float4(0.f, 0.f, 0.f, 0.f);
    #pragma unroll 8
    for (int k = 0; k < 128; ++k) {
        float4 w = ((float4*)sW[k])[tx];
        float x0 = sA[ty * 2 + 0][k];
        float x1 = sA[ty * 2 + 1][k];
        a0.x = fmaf(x0, w.x, a0.x); a0.y = fmaf(x0, w.y, a0.y);
        a0.z = fmaf(x0, w.z, a0.z); a0.w = fmaf(x0, w.w, a0.w);
        a1.x = fmaf(x1, w.x, a1.x); a1.y = fmaf(x1, w.y, a1.y);
        a1.z = fmaf(x1, w.z, a1.z); a1.w = fmaf(x1, w.w, a1.w);
    }

    #pragma unroll
    for (int ni = 0; ni < 2; ++ni) {
        int gn = n0 + ty * 2 + ni;
        if (gn < N_NODES) ((float4*)(t2 + (size_t)gn * 64))[tx] = ni ? a1 : a0;
    }
}

// ---------------- pull aggregation, 128 feats: one wave per node ----------------
// h1p[n] = relu(norm_in[n] * sum_{s->n} norm_out[s]*t1[s] + b1) * norm_out[n]
__global__ __launch_bounds__(256) void pull128_kernel(const float* __restrict__ x,
                                                      const int* __restrict__ row_ptr,
                                                      const int* __restrict__ eidx,
                                                      const float* __restrict__ b1,
                                                      const float* __restrict__ norm_in,
                                                      const float* __restrict__ norm_out,
                                                      float* __restrict__ out) {
    int node = blockIdx.x * 4 + (threadIdx.x >> 6);
    node = __builtin_amdgcn_readfirstlane(node);
    const int lane = threadIdx.x & 63;
    const int beg = row_ptr[node];
    const int end = row_ptr[node + 1];

    float2 acc0 = make_float2(0.f, 0.f);
    float2 acc1 = make_float2(0.f, 0.f);
    float2 acc2 = make_float2(0.f, 0.f);
    float2 acc3 = make_float2(0.f, 0.f);
    int j = beg;
    for (; j + 3 < end; j += 4) {
        int s0 = __builtin_amdgcn_readfirstlane(eidx[j]);
        int s1 = __builtin_amdgcn_readfirstlane(eidx[j + 1]);
        int s2 = __builtin_amdgcn_readfirstlane(eidx[j + 2]);
        int s3 = __builtin_amdgcn_readfirstlane(eidx[j + 3]);
        float n0 = norm_out[s0], n1 = norm_out[s1], n2 = norm_out[s2], n3 = norm_out[s3];
        float2 v0 = ((const float2*)(x + (size_t)s0 * 128))[lane];
        float2 v1 = ((const float2*)(x + (size_t)s1 * 128))[lane];
        float2 v2 = ((const float2*)(x + (size_t)s2 * 128))[lane];
        float2 v3 = ((const float2*)(x + (size_t)s3 * 128))[lane];
        acc0.x = fmaf(v0.x, n0, acc0.x); acc0.y = fmaf(v0.y, n0, acc0.y);
        acc1.x = fmaf(v1.x, n1, acc1.x); acc1.y = fmaf(v1.y, n1, acc1.y);
        acc2.x = fmaf(v2.x, n2, acc2.x); acc2.y = fmaf(v2.y, n2, acc2.y);
        acc3.x = fmaf(v3.x, n3, acc3.x); acc3.y = fmaf(v3.y, n3, acc3.y);
    }
    for (; j < end; ++j) {
        int s0 = __builtin_amdgcn_readfirstlane(eidx[j]);
        float n0 = norm_out[s0];
        float2 v0 = ((const float2*)(x + (size_t)s0 * 128))[lane];
        acc0.x = fmaf(v0.x, n0, acc0.x); acc0.y = fmaf(v0.y, n0, acc0.y);
    }
    float ni = norm_in[node];
    float no = norm_out[node];
    float2 bb = ((const float2*)b1)[lane];
    float sx = (acc0.x + acc1.x) + (acc2.x + acc3.x);
    float sy = (acc0.y + acc1.y) + (acc2.y + acc3.y);
    float2 r;
    r.x = fmaxf(fmaf(sx, ni, bb.x), 0.f) * no;
    r.y = fmaxf(fmaf(sy, ni, bb.y), 0.f) * no;
    ((float2*)(out + (size_t)node * 128))[lane] = r;
}

// ---------------- pull aggregation, 64 feats: one wave per node, half-wave per edge ----------------
// out[n] = relu(norm_in[n] * sum_{s->n} t2[s] + b2)
__global__ __launch_bounds__(256) void pull64_kernel(const float* __restrict__ x,
                                                     const int* __restrict__ row_ptr,
                                                     const int* __restrict__ eidx,
                                                     const float* __restrict__ b2,
                                                     const float* __restrict__ norm_in,
                                                     float* __restrict__ out) {
    int node = blockIdx.x * 4 + (threadIdx.x >> 6);
    node = __builtin_amdgcn_readfirstlane(node);
    const int lane = threadIdx.x & 63;
    const int half = lane >> 5;     // 0: even edges, 1: odd edges
    const int fl = lane & 31;       // feature group (float2)
    const int beg = row_ptr[node];
    const int end = row_ptr[node + 1];

    float2 acc0 = make_float2(0.f, 0.f);
    float2 acc1 = make_float2(0.f, 0.f);
    int j = beg + half;
    for (; j + 2 < end; j += 4) {
        int s0 = eidx[j], s1 = eidx[j + 2];
        float2 v0 = ((const float2*)(x + (size_t)s0 * 64))[fl];
        float2 v1 = ((const float2*)(x + (size_t)s1 * 64))[fl];
        acc0.x += v0.x; acc0.y += v0.y;
        acc1.x += v1.x; acc1.y += v1.y;
    }
    if (j < end) {
        int s0 = eidx[j];
        float2 v0 = ((const float2*)(x + (size_t)s0 * 64))[fl];
        acc0.x += v0.x; acc0.y += v0.y;
    }
    float ax = acc0.x + acc1.x, ay = acc0.y + acc1.y;
    ax += __shfl_xor(ax, 32, 64);
    ay += __shfl_xor(ay, 32, 64);
    if (half == 0) {
        float ni = norm_in[node];
        float2 bb = ((const float2*)b2)[fl];
        float2 r;
        r.x = fmaxf(fmaf(ax, ni, bb.x), 0.f);
        r.y = fmaxf(fmaf(ay, ni, bb.y), 0.f);
        ((float2*)(out + (size_t)node * 64))[fl] = r;
    }
}

extern "C" void kernel_launch(void* const* d_in, const int* in_sizes, int n_in,
                              void* d_out, int out_size, void* d_ws, size_t ws_size,
                              hipStream_t stream) {
    const float* h  = (const float*)d_in[0];
    const float* W1 = (const float*)d_in[1];
    const float* b1 = (const float*)d_in[2];
    const float* W2 = (const float*)d_in[3];
    const float* b2 = (const float*)d_in[4];
    const int* src  = (const int*)d_in[5];
    const int* dst  = (const int*)d_in[6];
    float* out = (float*)d_out;

    char* ws = (char*)d_ws;
    size_t off = 0;
    auto alloc = [&](size_t bytes) {
        void* p = ws + off;
        off = (off + bytes + 255) & ~(size_t)255;
        return p;
    };
    int* deg_in       = (int*)alloc(N_NODES * sizeof(int));
    unsigned* deg_out = (unsigned*)alloc(N_NODES * sizeof(unsigned));
    float* norm_out   = (float*)alloc(N_NODES * sizeof(float));
    float* norm_in    = (float*)alloc(N_NODES * sizeof(float));
    int* row_ptr      = (int*)alloc((N_NODES + 1) * sizeof(int));
    int* bsum         = (int*)alloc(SCAN_GRID * sizeof(int));
    int* eidx         = (int*)alloc((size_t)N_EDGES * sizeof(int));                // 3.2 MB
    float* t1         = (float*)alloc((size_t)N_NODES * 128 * sizeof(float));      // 25.6 MB (reused as t2)
    float* h1p        = (float*)alloc((size_t)N_NODES * 128 * sizeof(float));      // 25.6 MB
    int* rank         = (int*)h1p;   // rank dead before pull128 writes h1p
    float* t2         = t1;          // t1 dead after pull128

    // zero degree counters
    hipMemsetAsync(deg_in, 0, N_NODES * sizeof(int), stream);
    hipMemsetAsync(deg_out, 0, N_NODES * sizeof(unsigned), stream);

    // fused: degree/rank atomics (idle-heavy) + gemmA t1 = h @ W1 (VALU-heavy)
    fused1_kernel<<<DEG_BLOCKS + GEMMA_BLOCKS, 256, 0, stream>>>(
        src, dst, deg_in, deg_out, rank, h, W1, t1);

    // parallel scan -> row_ptr, plus norms
    scan1_kernel<<<SCAN_GRID, SCAN_BLK, 0, stream>>>(deg_in, row_ptr, bsum);
    scan2_kernel<<<1, 64, 0, stream>>>(bsum);
    scan3_norm_kernel<<<SCAN_GRID, SCAN_BLK, 0, stream>>>(row_ptr, bsum, deg_in, deg_out,
                                                          norm_out, norm_in);

    // atomic-free CSR placement
    place_kernel<<<(N_EDGES + 255) / 256, 256, 0, stream>>>(src, dst, row_ptr, rank, eidx);

    // layer 1 pull (norm_out applied per-edge as wave-uniform scalar)
    pull128_kernel<<<N_NODES / 4, 256, 0, stream>>>(t1, row_ptr, eidx, b1, norm_in, norm_out, h1p);

    // layer 2
    gemmB_kernel<<<(N_NODES + 31) / 32, 256, 0, stream>>>(h1p, W2, t2);
    pull64_kernel<<<N_NODES / 4, 256, 0, stream>>>(t2, row_ptr, eidx, b2, norm_in, out);
}

// Round 5
// 268.625 us; speedup vs baseline: 10.7648x; 1.1291x over previous
//
#include <hip/hip_runtime.h>

#define N_NODES 50000
#define N_EDGES 800000
#define IN_SIZE 128
#define HIDDEN 128
#define OUT_SIZE 64

#define DEG_CHUNKS 782      // 782*1024 >= 800000 edges, 4 edges/thread
#define GEMMA_TILES 1563    // ceil(50000/32)
#define FUSED1_GRID (3 * DEG_CHUNKS)   // role = blockIdx%3: 0 -> deg, 1/2 -> gemm
#define SCAN_BLK 1024
#define SCAN_GRID 49        // 49*1024 = 50176 >= 50000

static __device__ inline unsigned pack_bf16x2(float a, float b) {
    unsigned ua = __float_as_uint(a);
    unsigned ub = __float_as_uint(b);
    unsigned ra = (ua + 0x7fffu + ((ua >> 16) & 1u)) >> 16;        // RNE
    unsigned rb = (ub + 0x7fffu + ((ub >> 16) & 1u)) & 0xffff0000u;
    return ra | rb;
}

// ---- fused launch 1: interleaved deg/rank blocks + gemmA blocks ----
// deg role:  rank[e] = deg_in[dst]++;  deg_out[src]++   (memory-side atomics)
// gemm role: t1 = bf16(h @ W1)  (norm_out applied per-edge in pull128)
__global__ __launch_bounds__(256) void fused1_kernel(const int* __restrict__ src,
                                                     const int* __restrict__ dst,
                                                     int* __restrict__ deg_in,
                                                     unsigned* __restrict__ deg_out,
                                                     int* __restrict__ rank,
                                                     const float* __restrict__ h,
                                                     const float* __restrict__ W1,
                                                     unsigned short* __restrict__ t1) {
    __shared__ float sA[32][128];
    __shared__ float sW[32][128];

    const int g = blockIdx.x / 3;
    const int r = blockIdx.x - 3 * g;

    if (r == 0) {
        // degree/rank role: 1024-edge chunk, 4 strided coalesced rounds
        const int base = g * 1024 + threadIdx.x;
        #pragma unroll
        for (int i = 0; i < 4; ++i) {
            int e = base + i * 256;
            if (e < N_EDGES) {
                int s = src[e];
                int d = dst[e];
                rank[e] = atomicAdd(&deg_in[d], 1);
                atomicAdd(&deg_out[s], 1u);
            }
        }
        return;
    }

    const int tile = g * 2 + (r - 1);
    if (tile >= GEMMA_TILES) return;

    const int t  = threadIdx.x;
    const int tx = t & 31;
    const int ty = t >> 5;
    const int n0 = tile * 32;

    for (int i = t; i < 1024; i += 256) {
        int n = i >> 5, c = i & 31;
        int gn = n0 + n;
        float4 v = make_float4(0.f, 0.f, 0.f, 0.f);
        if (gn < N_NODES) v = ((const float4*)(h + (size_t)gn * 128))[c];
        ((float4*)sA[n])[c] = v;
    }

    float4 acc[4];
    #pragma unroll
    for (int i = 0; i < 4; ++i) acc[i] = make_float4(0.f, 0.f, 0.f, 0.f);

    for (int kc = 0; kc < 4; ++kc) {
        __syncthreads();
        for (int i = t; i < 1024; i += 256) {
            int k = i >> 5, c = i & 31;
            ((float4*)sW[k])[c] = ((const float4*)(W1 + (size_t)(kc * 32 + k) * 128))[c];
        }
        __syncthreads();
        #pragma unroll 8
        for (int k = 0; k < 32; ++k) {
            float4 w = ((float4*)sW[k])[tx];
            #pragma unroll
            for (int ni = 0; ni < 4; ++ni) {
                float a = sA[ty * 4 + ni][kc * 32 + k];
                acc[ni].x = fmaf(a, w.x, acc[ni].x);
                acc[ni].y = fmaf(a, w.y, acc[ni].y);
                acc[ni].z = fmaf(a, w.z, acc[ni].z);
                acc[ni].w = fmaf(a, w.w, acc[ni].w);
            }
        }
    }

    #pragma unroll
    for (int ni = 0; ni < 4; ++ni) {
        int gn = n0 + ty * 4 + ni;
        if (gn < N_NODES) {
            uint2 p;
            p.x = pack_bf16x2(acc[ni].x, acc[ni].y);
            p.y = pack_bf16x2(acc[ni].z, acc[ni].w);
            ((uint2*)(t1 + (size_t)gn * 128))[tx] = p;
        }
    }
}

// ---- scan phase 1: per-block exclusive scan of deg_in, emit block sums ----
__global__ __launch_bounds__(SCAN_BLK) void scan1_kernel(const int* __restrict__ deg_in,
                                                         int* __restrict__ row_ptr,
                                                         int* __restrict__ bsum) {
    __shared__ int wsum[16];
    const int t = threadIdx.x, lane = t & 63, w = t >> 6;
    const int i = blockIdx.x * SCAN_BLK + t;
    int v = (i < N_NODES) ? deg_in[i] : 0;
    int incl = v;
    #pragma unroll
    for (int d = 1; d < 64; d <<= 1) {
        int u = __shfl_up(incl, d, 64);
        if (lane >= d) incl += u;
    }
    if (lane == 63) wsum[w] = incl;
    __syncthreads();
    int woff = 0, total = 0;
    #pragma unroll
    for (int j = 0; j < 16; ++j) {
        int s = wsum[j];
        if (j < w) woff += s;
        total += s;
    }
    if (i < N_NODES) row_ptr[i] = woff + incl - v;
    if (t == 0) bsum[blockIdx.x] = total;
}

// ---- scan phase 2: exclusive scan of 49 block sums (single wave) ----
__global__ __launch_bounds__(64) void scan2_kernel(int* __restrict__ bsum) {
    const int t = threadIdx.x;
    int v = (t < SCAN_GRID) ? bsum[t] : 0;
    int incl = v;
    #pragma unroll
    for (int d = 1; d < 64; d <<= 1) {
        int u = __shfl_up(incl, d, 64);
        if (t >= d) incl += u;
    }
    if (t < SCAN_GRID) bsum[t] = incl - v;
}

// ---- scan phase 3 + norms ----
__global__ __launch_bounds__(SCAN_BLK) void scan3_norm_kernel(int* __restrict__ row_ptr,
                                                              const int* __restrict__ bsum,
                                                              const int* __restrict__ deg_in,
                                                              const unsigned* __restrict__ deg_out,
                                                              float* __restrict__ norm_out,
                                                              float* __restrict__ norm_in) {
    const int i = blockIdx.x * SCAN_BLK + threadIdx.x;
    if (i < N_NODES) {
        row_ptr[i] += bsum[blockIdx.x];
        unsigned a = deg_out[i]; if (a == 0u) a = 1u;
        int b = deg_in[i];       if (b == 0)  b = 1;
        norm_out[i] = rsqrtf((float)a);
        norm_in[i]  = rsqrtf((float)b);
    }
    if (i == 0) row_ptr[N_NODES] = N_EDGES;
}

// ---- atomic-free CSR placement ----
__global__ __launch_bounds__(256) void place_kernel(const int* __restrict__ src,
                                                    const int* __restrict__ dst,
                                                    const int* __restrict__ row_ptr,
                                                    const int* __restrict__ rank,
                                                    int* __restrict__ eidx) {
    int e = blockIdx.x * 256 + threadIdx.x;
    if (e < N_EDGES) eidx[row_ptr[dst[e]] + rank[e]] = src[e];
}

// ---------------- GEMM-B: t2 = h1p @ W2  (N x 128 @ 128 x 64) ----------------
__global__ __launch_bounds__(256) void gemmB_kernel(const float* __restrict__ h1p,
                                                    const float* __restrict__ W2,
                                                    float* __restrict__ t2) {
    __shared__ float sA[32][128];
    __shared__ float sW[128][64];
    const int t  = threadIdx.x;
    const int tx = t & 15;
    const int ty = t >> 4;
    const int n0 = blockIdx.x * 32;

    for (int i = t; i < 1024; i += 256) {
        int n = i >> 5, c = i & 31;
        int gn = n0 + n;
        float4 v = make_float4(0.f, 0.f, 0.f, 0.f);
        if (gn < N_NODES) v = ((const float4*)(h1p + (size_t)gn * 128))[c];
        ((float4*)sA[n])[c] = v;
    }
    for (int i = t; i < 2048; i += 256) {
        int k = i >> 4, c = i & 15;
        ((float4*)sW[k])[c] = ((const float4*)(W2 + (size_t)k * 64))[c];
    }
    __syncthreads();

    float4 a0 = make_float4(0.f, 0.f, 0.f, 0.f);
    float4 a1 = make_float4(0.f, 0.f, 0.f, 0.f);
    #pragma unroll 8
    for (int k = 0; k < 128; ++k) {
        float4 w = ((float4*)sW[k])[tx];
        float x0 = sA[ty * 2 + 0][k];
        float x1 = sA[ty * 2 + 1][k];
        a0.x = fmaf(x0, w.x, a0.x); a0.y = fmaf(x0, w.y, a0.y);
        a0.z = fmaf(x0, w.z, a0.z); a0.w = fmaf(x0, w.w, a0.w);
        a1.x = fmaf(x1, w.x, a1.x); a1.y = fmaf(x1, w.y, a1.y);
        a1.z = fmaf(x1, w.z, a1.z); a1.w = fmaf(x1, w.w, a1.w);
    }

    #pragma unroll
    for (int ni = 0; ni < 2; ++ni) {
        int gn = n0 + ty * 2 + ni;
        if (gn < N_NODES) ((float4*)(t2 + (size_t)gn * 64))[tx] = ni ? a1 : a0;
    }
}

// ---------------- pull aggregation, 128 bf16 feats: one wave per node ----------------
// h1p[n] = relu(norm_in[n] * sum_{s->n} norm_out[s]*t1[s] + b1) * norm_out[n]
__global__ __launch_bounds__(256) void pull128_kernel(const unsigned short* __restrict__ xb,
                                                      const int* __restrict__ row_ptr,
                                                      const int* __restrict__ eidx,
                                                      const float* __restrict__ b1,
                                                      const float* __restrict__ norm_in,
                                                      const float* __restrict__ norm_out,
                                                      float* __restrict__ out) {
    int node = blockIdx.x * 4 + (threadIdx.x >> 6);
    node = __builtin_amdgcn_readfirstlane(node);
    const int lane = threadIdx.x & 63;
    const int beg = row_ptr[node];
    const int end = row_ptr[node + 1];

    float2 acc0 = make_float2(0.f, 0.f);
    float2 acc1 = make_float2(0.f, 0.f);
    float2 acc2 = make_float2(0.f, 0.f);
    float2 acc3 = make_float2(0.f, 0.f);
    int j = beg;
    for (; j + 3 < end; j += 4) {
        int s0 = __builtin_amdgcn_readfirstlane(eidx[j]);
        int s1 = __builtin_amdgcn_readfirstlane(eidx[j + 1]);
        int s2 = __builtin_amdgcn_readfirstlane(eidx[j + 2]);
        int s3 = __builtin_amdgcn_readfirstlane(eidx[j + 3]);
        float n0 = norm_out[s0], n1 = norm_out[s1], n2 = norm_out[s2], n3 = norm_out[s3];
        unsigned u0 = ((const unsigned*)(xb + (size_t)s0 * 128))[lane];
        unsigned u1 = ((const unsigned*)(xb + (size_t)s1 * 128))[lane];
        unsigned u2 = ((const unsigned*)(xb + (size_t)s2 * 128))[lane];
        unsigned u3 = ((const unsigned*)(xb + (size_t)s3 * 128))[lane];
        acc0.x = fmaf(__uint_as_float(u0 << 16), n0, acc0.x);
        acc0.y = fmaf(__uint_as_float(u0 & 0xffff0000u), n0, acc0.y);
        acc1.x = fmaf(__uint_as_float(u1 << 16), n1, acc1.x);
        acc1.y = fmaf(__uint_as_float(u1 & 0xffff0000u), n1, acc1.y);
        acc2.x = fmaf(__uint_as_float(u2 << 16), n2, acc2.x);
        acc2.y = fmaf(__uint_as_float(u2 & 0xffff0000u), n2, acc2.y);
        acc3.x = fmaf(__uint_as_float(u3 << 16), n3, acc3.x);
        acc3.y = fmaf(__uint_as_float(u3 & 0xffff0000u), n3, acc3.y);
    }
    for (; j < end; ++j) {
        int s0 = __builtin_amdgcn_readfirstlane(eidx[j]);
        float n0 = norm_out[s0];
        unsigned u0 = ((const unsigned*)(xb + (size_t)s0 * 128))[lane];
        acc0.x = fmaf(__uint_as_float(u0 << 16), n0, acc0.x);
        acc0.y = fmaf(__uint_as_float(u0 & 0xffff0000u), n0, acc0.y);
    }
    float ni = norm_in[node];
    float no = norm_out[node];
    float2 bb = ((const float2*)b1)[lane];
    float sx = (acc0.x + acc1.x) + (acc2.x + acc3.x);
    float sy = (acc0.y + acc1.y) + (acc2.y + acc3.y);
    float2 r;
    r.x = fmaxf(fmaf(sx, ni, bb.x), 0.f) * no;
    r.y = fmaxf(fmaf(sy, ni, bb.y), 0.f) * no;
    ((float2*)(out + (size_t)node * 128))[lane] = r;
}

// ---------------- pull aggregation, 64 fp32 feats ----------------
// out[n] = relu(norm_in[n] * sum_{s->n} t2[s] + b2)
__global__ __launch_bounds__(256) void pull64_kernel(const float* __restrict__ x,
                                                     const int* __restrict__ row_ptr,
                                                     const int* __restrict__ eidx,
                                                     const float* __restrict__ b2,
                                                     const float* __restrict__ norm_in,
                                                     float* __restrict__ out) {
    int node = blockIdx.x * 4 + (threadIdx.x >> 6);
    node = __builtin_amdgcn_readfirstlane(node);
    const int lane = threadIdx.x & 63;
    const int half = lane >> 5;
    const int fl = lane & 31;
    const int beg = row_ptr[node];
    const int end = row_ptr[node + 1];

    float2 acc0 = make_float2(0.f, 0.f);
    float2 acc1 = make_float2(0.f, 0.f);
    int j = beg + half;
    for (; j + 2 < end; j += 4) {
        int s0 = eidx[j], s1 = eidx[j + 2];
        float2 v0 = ((const float2*)(x + (size_t)s0 * 64))[fl];
        float2 v1 = ((const float2*)(x + (size_t)s1 * 64))[fl];
        acc0.x += v0.x; acc0.y += v0.y;
        acc1.x += v1.x; acc1.y += v1.y;
    }
    if (j < end) {
        int s0 = eidx[j];
        float2 v0 = ((const float2*)(x + (size_t)s0 * 64))[fl];
        acc0.x += v0.x; acc0.y += v0.y;
    }
    float ax = acc0.x + acc1.x, ay = acc0.y + acc1.y;
    ax += __shfl_xor(ax, 32, 64);
    ay += __shfl_xor(ay, 32, 64);
    if (half == 0) {
        float ni = norm_in[node];
        float2 bb = ((const float2*)b2)[fl];
        float2 r;
        r.x = fmaxf(fmaf(ax, ni, bb.x), 0.f);
        r.y = fmaxf(fmaf(ay, ni, bb.y), 0.f);
        ((float2*)(out + (size_t)node * 64))[fl] = r;
    }
}

extern "C" void kernel_launch(void* const* d_in, const int* in_sizes, int n_in,
                              void* d_out, int out_size, void* d_ws, size_t ws_size,
                              hipStream_t stream) {
    const float* h  = (const float*)d_in[0];
    const float* W1 = (const float*)d_in[1];
    const float* b1 = (const float*)d_in[2];
    const float* W2 = (const float*)d_in[3];
    const float* b2 = (const float*)d_in[4];
    const int* src  = (const int*)d_in[5];
    const int* dst  = (const int*)d_in[6];
    float* out = (float*)d_out;

    char* ws = (char*)d_ws;
    size_t off = 0;
    auto alloc = [&](size_t bytes) {
        void* p = ws + off;
        off = (off + bytes + 255) & ~(size_t)255;
        return p;
    };
    int* deg_in       = (int*)alloc(N_NODES * sizeof(int));
    unsigned* deg_out = (unsigned*)alloc(N_NODES * sizeof(unsigned));
    float* norm_out   = (float*)alloc(N_NODES * sizeof(float));
    float* norm_in    = (float*)alloc(N_NODES * sizeof(float));
    int* row_ptr      = (int*)alloc((N_NODES + 1) * sizeof(int));
    int* bsum         = (int*)alloc(SCAN_GRID * sizeof(int));
    int* eidx         = (int*)alloc((size_t)N_EDGES * sizeof(int));                       // 3.2 MB
    unsigned short* t1 = (unsigned short*)alloc((size_t)N_NODES * 128 * sizeof(short));   // 12.8 MB (bf16; reused as fp32 t2)
    float* h1p        = (float*)alloc((size_t)N_NODES * 128 * sizeof(float));             // 25.6 MB
    int* rank         = (int*)h1p;       // rank dead before pull128 writes h1p
    float* t2         = (float*)t1;      // t1 dead after pull128; 50000*64*4 = 12.8 MB fits

    hipMemsetAsync(deg_in, 0, N_NODES * sizeof(int), stream);
    hipMemsetAsync(deg_out, 0, N_NODES * sizeof(unsigned), stream);

    // fused + interleaved: degree/rank atomics co-resident with gemmA (t1 = bf16(h @ W1))
    fused1_kernel<<<FUSED1_GRID, 256, 0, stream>>>(src, dst, deg_in, deg_out, rank, h, W1, t1);

    // parallel scan -> row_ptr, plus norms
    scan1_kernel<<<SCAN_GRID, SCAN_BLK, 0, stream>>>(deg_in, row_ptr, bsum);
    scan2_kernel<<<1, 64, 0, stream>>>(bsum);
    scan3_norm_kernel<<<SCAN_GRID, SCAN_BLK, 0, stream>>>(row_ptr, bsum, deg_in, deg_out,
                                                          norm_out, norm_in);

    // atomic-free CSR placement
    place_kernel<<<(N_EDGES + 255) / 256, 256, 0, stream>>>(src, dst, row_ptr, rank, eidx);

    // layer 1 pull (bf16 gather; norm_out applied per-edge as wave-uniform scalar)
    pull128_kernel<<<N_NODES / 4, 256, 0, stream>>>(t1, row_ptr, eidx, b1, norm_in, norm_out, h1p);

    // layer 2
    gemmB_kernel<<<(N_NODES + 31) / 32, 256, 0, stream>>>(h1p, W2, t2);
    pull64_kernel<<<N_NODES / 4, 256, 0, stream>>>(t2, row_ptr, eidx, b2, norm_in, out);
}